// Round 8
// baseline (2810.481 us; speedup 1.0000x reference)
//
#include <hip/hip_runtime.h>

#define N_NODES 50000
#define N_EDGES 1000000
#define N_ETYPES 3

typedef _Float16 f16x8 __attribute__((ext_vector_type(8)));
typedef float f32x4 __attribute__((ext_vector_type(4)));

// ---------- Kernel 0: W[e][k][n] fp32 -> Wt[e][n][k] fp16 ----------
__global__ void k_prep_w(const float* __restrict__ W, _Float16* __restrict__ Wt) {
    int e  = blockIdx.y;
    int id = blockIdx.x * blockDim.x + threadIdx.x;   // 0..32767
    int k  = id >> 7;
    int n  = id & 127;
    Wt[(size_t)e * 32768 + (size_t)n * 256 + k] =
        (_Float16)W[(size_t)e * 32768 + (size_t)k * 128 + n];
}

// ---------- Kernel 1: Wh[e] = fp16( x @ W[e] + b[e] )  (MFMA, no LDS) ----------
// B (Wt) is 64KB/etype -> L2-resident; fragments read straight from global.
// Fragment maps (m89/m91-verified; empirically re-verified here by rounds 2/3/4
// producing bit-identical outputs vs the scalar GEMM):
//   A[m=lane&15][k=quad*8+j], B^T row = lane&15, D: col=lane&15, row=quad*4+reg.
__global__ __launch_bounds__(256) void k_gemm(
    const float* __restrict__ x,             // [N,256] fp32
    const _Float16* __restrict__ Wt,         // [3][128][256] fp16 (W^T)
    const float* __restrict__ b,             // [3][128] fp32
    unsigned short* __restrict__ Wh)         // [3][N][128] fp16 bits
{
    const int e    = blockIdx.y;
    const int tid  = threadIdx.x;
    const int lane = tid & 63;
    const int w    = tid >> 6;       // wave 0..3
    const int q    = lane >> 4;      // quad 0..3
    const int c    = lane & 15;      // m for A, n for B/D
    const int rowBase = blockIdx.x * 256;
    const _Float16* Bt = Wt + (size_t)e * 32768;   // [128][256]

    f32x4 acc[4][8];
    #pragma unroll
    for (int mt = 0; mt < 4; ++mt)
        #pragma unroll
        for (int nt = 0; nt < 8; ++nt)
            acc[mt][nt] = (f32x4){0.f, 0.f, 0.f, 0.f};

    int arow[4];
    #pragma unroll
    for (int mt = 0; mt < 4; ++mt) {
        int r = rowBase + w * 64 + mt * 16 + c;
        arow[mt] = (r < N_NODES) ? r : (N_NODES - 1);   // clamp; discarded at store
    }

    #pragma unroll
    for (int ks = 0; ks < 8; ++ks) {           // K = 256 = 8 * 32
        f16x8 afrag[4];
        #pragma unroll
        for (int mt = 0; mt < 4; ++mt) {
            const float* xp = x + (size_t)arow[mt] * 256 + ks * 32 + q * 8;
            f32x4 lo = *(const f32x4*)xp;
            f32x4 hi = *(const f32x4*)(xp + 4);
            f16x8 af;
            #pragma unroll
            for (int j = 0; j < 4; ++j) {
                af[j]     = (_Float16)lo[j];
                af[j + 4] = (_Float16)hi[j];
            }
            afrag[mt] = af;
        }
        #pragma unroll
        for (int nt = 0; nt < 8; ++nt) {
            f16x8 bfrag = *(const f16x8*)(Bt + (size_t)(nt * 16 + c) * 256 + ks * 32 + q * 8);
            #pragma unroll
            for (int mt = 0; mt < 4; ++mt)
                acc[mt][nt] = __builtin_amdgcn_mfma_f32_16x16x32_f16(
                    afrag[mt], bfrag, acc[mt][nt], 0, 0, 0);
        }
    }

    const size_t whBase = (size_t)e * N_NODES * 128;
    #pragma unroll
    for (int nt = 0; nt < 8; ++nt) {
        float bias = b[e * 128 + nt * 16 + c];
        #pragma unroll
        for (int mt = 0; mt < 4; ++mt) {
            int baseRow = rowBase + w * 64 + mt * 16 + q * 4;
            #pragma unroll
            for (int r = 0; r < 4; ++r) {
                int row = baseRow + r;
                if (row < N_NODES) {
                    float v = acc[mt][nt][r] + bias;
                    Wh[whBase + (size_t)row * 128 + nt * 16 + c] =
                        __builtin_bit_cast(unsigned short, (_Float16)v);
                }
            }
        }
    }
}

// ---------- Kernel 2: edge scatter-add (one edge per wave) ----------
// Reference semantics: msgs = Wh[src]; segment-sum onto dst.
__global__ void k_scatter(const int* __restrict__ src, const int* __restrict__ dst,
                          const unsigned short* __restrict__ Wh,
                          float* __restrict__ sums, float* __restrict__ deg)
{
    const int lane = threadIdx.x & 63;
    const int wid  = blockIdx.x * (blockDim.x >> 6) + (threadIdx.x >> 6);
    const int nw   = gridDim.x * (blockDim.x >> 6);
    for (int e = 0; e < N_ETYPES; ++e) {
        const int* se = src + (size_t)e * N_EDGES;
        const int* de = dst + (size_t)e * N_EDGES;
        const size_t nbase = (size_t)e * N_NODES;
        for (int i = wid; i < N_EDGES; i += nw) {
            int s = __builtin_amdgcn_readfirstlane(se[i]);
            int d = __builtin_amdgcn_readfirstlane(de[i]);
            // 64 lanes x 4B = 256B coalesced row read (2 fp16 per lane)
            unsigned u = ((const unsigned*)(Wh + (nbase + s) * 128))[lane];
            float f0 = (float)__builtin_bit_cast(_Float16, (unsigned short)(u & 0xFFFFu));
            float f1 = (float)__builtin_bit_cast(_Float16, (unsigned short)(u >> 16));
            float* srow = sums + (nbase + d) * 128 + 2 * lane;
            unsafeAtomicAdd(srow, f0);
            unsafeAtomicAdd(srow + 1, f1);
            if (lane == 0) unsafeAtomicAdd(deg + nbase + d, 1.0f);
        }
    }
}

// ---------- Kernel 3: mean + transpose to [N, 3, 128] fp32 OUTPUT ----------
__global__ void k_finalize(const float* __restrict__ sums, const float* __restrict__ deg,
                           float* __restrict__ out)
{
    int id = blockIdx.x * blockDim.x + threadIdx.x;   // over 50000*3*64
    if (id >= N_NODES * N_ETYPES * 64) return;
    int n   = id / 192;
    int rem = id - n * 192;
    int e   = rem >> 6;
    int c   = (rem & 63) << 1;
    float dg = deg[(size_t)e * N_NODES + n];
    float2 sv = *(const float2*)(sums + ((size_t)e * N_NODES + n) * 128 + c);
    float inv = (dg > 0.f) ? (1.0f / dg) : 0.f;   // deg==0 -> out 0 (sums are 0)
    float2 o;
    o.x = sv.x * inv;
    o.y = sv.y * inv;
    *(float2*)(out + (size_t)n * 384 + (size_t)e * 128 + c) = o;
}

// ---------- launch ----------
extern "C" void kernel_launch(void* const* d_in, const int* in_sizes, int n_in,
                              void* d_out, int out_size, void* d_ws, size_t ws_size,
                              hipStream_t stream) {
    const float* x    = (const float*)d_in[0];
    const int*   esrc = (const int*)d_in[1];
    const int*   edst = (const int*)d_in[2];
    const float* W    = (const float*)d_in[3];
    const float* bias = (const float*)d_in[4];
    float*       out  = (float*)d_out;            // fp32 output [N,3,128]

    char* ws = (char*)d_ws;
    _Float16*       Wt = (_Float16*)ws;                        //    196,608 B
    unsigned short* Wh = (unsigned short*)(ws + 196608);       // 38,400,000 B
    float* sums        = (float*)(ws + 196608 + 38400000);     // 76,800,000 B
    float* deg         = (float*)(ws + 196608 + 38400000 + 76800000);  // 600,000 B

    // zero accumulators (sums + deg are contiguous)
    hipMemsetAsync(sums, 0, 76800000 + 600000, stream);

    k_prep_w<<<dim3(128, 3), 256, 0, stream>>>(W, Wt);
    k_gemm<<<dim3(196, 3), 256, 0, stream>>>(x, Wt, bias, Wh);
    k_scatter<<<dim3(2048), 256, 0, stream>>>(esrc, edst, Wh, sums, deg);
    k_finalize<<<dim3((N_NODES * N_ETYPES * 64 + 255) / 256), 256, 0, stream>>>(sums, deg, out);
}